// Round 5
// baseline (89.186 us; speedup 1.0000x reference)
//
#include <hip/hip_runtime.h>

#define NW 10

// DPP helpers: quad_perm xor1=0xB1, xor2=0x4E; row_ror:8 (=xor8 within 16) = 0x128
template<int CTRL>
__device__ __forceinline__ float fdpp(float v) {
    return __int_as_float(__builtin_amdgcn_mov_dpp(__float_as_int(v), CTRL, 0xF, 0xF, true));
}
// ds_swizzle BitMode: offset = xor<<10 | 0x1F. xor4=0x101F, xor16=0x401F
template<int PAT>
__device__ __forceinline__ float fswz(float v) {
    return __int_as_float(__builtin_amdgcn_ds_swizzle(__float_as_int(v), PAT));
}

// State layout (4 waves/batch): s = W<<8 | lane<<2 | r, W=wave (s[9:8]), lane=s[7:2], r=s[1:0]
// LDS/table element index: e(s) = lane | r<<6 | W<<8
// ---------------- precompute: 14 diag phase tables + 80 RY (cos,sin) pairs ----------------
__global__ void precompute_kernel(const float* __restrict__ params, float2* __restrict__ tab) {
    const int d = blockIdx.x;
    const int j = threadIdx.x;
    if (d < 14) {
        int k, row;
        if (d < 3)       { k = d + 1;  row = 0; }
        else if (d < 7)  { k = d - 3;  row = 2; }
        else if (d < 11) { k = d - 7;  row = 3; }
        else             { k = d - 11; row = 5; }
        const float* th = params + (k * 6 + row) * NW;
        const int lane = j & 63, r = (j >> 6) & 3, W = (j >> 8) & 3;
        const int s = (W << 8) | (lane << 2) | r;
        float ang = 0.f;
#pragma unroll
        for (int w = 0; w < NW; ++w)
            ang += th[w] * (((s >> (9 - w)) & 1) ? 0.5f : -0.5f);
        float sn, cs;
        __sincosf(ang, &sn, &cs);
        tab[d * 1024 + j] = make_float2(cs, sn);
    } else if (j < 80) {
        const int ry = j / NW, w = j % NW;
        const int k = ry >> 1, i = ry & 1;
        const float* th = params + (k * 6 + (i ? 4 : 1)) * NW;
        float sn, cs;
        __sincosf(0.5f * th[w], &sn, &cs);
        tab[14 * 1024 + j] = make_float2(cs, sn);
    }
}

// ---------------- main kernel ----------------
__global__ __launch_bounds__(256, 8) void qsim_kernel(const float* __restrict__ x,
                                                      const float2* __restrict__ tab,
                                                      float* __restrict__ out) {
    __shared__ float2 buf[2][1024];
    __shared__ float sred[4][NW];

    const int t     = threadIdx.x;
    const int W     = t >> 6;                 // s[9:8]
    const int lane  = t & 63;                 // s[7:2]
    const int b     = blockIdx.x;
    const int ebase = lane | (W << 8);
    const float2* ry_tab = tab + 14 * 1024;

    float re[4], im[4];
#pragma unroll
    for (int r = 0; r < 4; ++r) { re[r] = 0.f; im[r] = 0.f; }
    if (t == 0) re[0] = 1.f;

    // perm gather element indices: new[s]=old[q], q = s^(s>>1)^((s&1)*0x300)
    int geidx[4];
#pragma unroll
    for (int r = 0; r < 4; ++r) {
        const int s = (W << 8) | (lane << 2) | r;
        const int q = s ^ (s >> 1) ^ ((r & 1) * 0x300);
        geidx[r] = ((q >> 2) & 63) | ((q & 3) << 6) | ((q >> 8) << 8);
    }

    // x-phase e^{iA_x(s)}, computed once, reused for 3 encoding diagonals
    const float* xb = x + b * NW;
    float xr[4], xi[4];
    {
        float xv[NW];
#pragma unroll
        for (int w = 0; w < NW; ++w) xv[w] = xb[w];
        float A = 0.f;
#pragma unroll
        for (int w = 0; w < NW; ++w) A += xv[w];
        float hi = -0.5f * A;
        if (W & 2) hi += xv[0];
        if (W & 1) hi += xv[1];
#pragma unroll
        for (int j = 0; j < 6; ++j)
            hi += ((lane >> j) & 1) ? xv[7 - j] : 0.f;
        float lo[4];
        lo[0] = 0.f;     lo[1] = xv[9];
        lo[2] = xv[8];   lo[3] = xv[8] + xv[9];
#pragma unroll
        for (int r = 0; r < 4; ++r)
            __sincosf(hi + lo[r], &xi[r], &xr[r]);
    }

    int bs = 0;

    auto tdiag = [&](int d) {
        const float2* tb = tab + (d << 10) + ebase;
#pragma unroll
        for (int r = 0; r < 4; ++r) {
            const float2 p = tb[r << 6];
            const float a = re[r], bb = im[r];
            re[r] = a * p.x - bb * p.y;
            im[r] = a * p.y + bb * p.x;
        }
    };
    auto txdiag = [&](int d) {
        const float2* tb = tab + (d << 10) + ebase;
#pragma unroll
        for (int r = 0; r < 4; ++r) {
            const float2 p = tb[r << 6];
            const float cx = p.x * xr[r] - p.y * xi[r];
            const float sx = p.x * xi[r] + p.y * xr[r];
            const float a = re[r], bb = im[r];
            re[r] = a * cx - bb * sx;
            im[r] = a * sx + bb * cx;
        }
    };

    auto ry = [&](int ridx) {
        const float2* rt = ry_tab + ridx * NW;
        // reg-bit wires: wire 9 (bit0, m=1), wire 8 (bit1, m=2)
#pragma unroll
        for (int kb = 0; kb < 2; ++kb) {
            const float2 cw = rt[9 - kb];
            const int m = 1 << kb;
#pragma unroll
            for (int r = 0; r < 4; ++r) {
                if (!(r & m)) {
                    const int r2 = r | m;
                    float a = re[r], bb = re[r2];
                    re[r]  = cw.x * a - cw.y * bb;
                    re[r2] = cw.y * a + cw.x * bb;
                    float ai = im[r], bi = im[r2];
                    im[r]  = cw.x * ai - cw.y * bi;
                    im[r2] = cw.y * ai + cw.x * bi;
                }
            }
        }
        // lane wires: wire 7-j acts on lane bit j
        {   // j=0: xor1
            const float2 cw = rt[7];
            const float ss = (lane & 1) ? cw.y : -cw.y;
#pragma unroll
            for (int r = 0; r < 4; ++r) {
                float pre = fdpp<0xB1>(re[r]), pim = fdpp<0xB1>(im[r]);
                re[r] = cw.x * re[r] + ss * pre;
                im[r] = cw.x * im[r] + ss * pim;
            }
        }
        {   // j=1: xor2
            const float2 cw = rt[6];
            const float ss = (lane & 2) ? cw.y : -cw.y;
#pragma unroll
            for (int r = 0; r < 4; ++r) {
                float pre = fdpp<0x4E>(re[r]), pim = fdpp<0x4E>(im[r]);
                re[r] = cw.x * re[r] + ss * pre;
                im[r] = cw.x * im[r] + ss * pim;
            }
        }
        {   // j=2: xor4
            const float2 cw = rt[5];
            const float ss = (lane & 4) ? cw.y : -cw.y;
#pragma unroll
            for (int r = 0; r < 4; ++r) {
                float pre = fswz<0x101F>(re[r]), pim = fswz<0x101F>(im[r]);
                re[r] = cw.x * re[r] + ss * pre;
                im[r] = cw.x * im[r] + ss * pim;
            }
        }
        {   // j=3: xor8 (row_ror:8)
            const float2 cw = rt[4];
            const float ss = (lane & 8) ? cw.y : -cw.y;
#pragma unroll
            for (int r = 0; r < 4; ++r) {
                float pre = fdpp<0x128>(re[r]), pim = fdpp<0x128>(im[r]);
                re[r] = cw.x * re[r] + ss * pre;
                im[r] = cw.x * im[r] + ss * pim;
            }
        }
        {   // j=4: xor16
            const float2 cw = rt[3];
            const float ss = (lane & 16) ? cw.y : -cw.y;
#pragma unroll
            for (int r = 0; r < 4; ++r) {
                float pre = fswz<0x401F>(re[r]), pim = fswz<0x401F>(im[r]);
                re[r] = cw.x * re[r] + ss * pre;
                im[r] = cw.x * im[r] + ss * pim;
            }
        }
        {   // j=5: xor32
            const float2 cw = rt[2];
            const float ss = (lane & 32) ? cw.y : -cw.y;
#pragma unroll
            for (int r = 0; r < 4; ++r) {
                float pre = __shfl_xor(re[r], 32, 64), pim = __shfl_xor(im[r], 32, 64);
                re[r] = cw.x * re[r] + ss * pre;
                im[r] = cw.x * im[r] + ss * pim;
            }
        }
        // wave wires 0 (bit9) and 1 (bit8), fused: R0 (x) R1, one LDS round-trip
        {
            const float2 c0 = rt[0], c1 = rt[1];
            float2* B = buf[bs]; bs ^= 1;
#pragma unroll
            for (int r = 0; r < 4; ++r)
                B[ebase + (r << 6)] = make_float2(re[r], im[r]);
            __syncthreads();
            // f(v==b)=c ; f(v!=b) = b ? +s : -s
            const float a1 = (W & 2) ? c0.y : -c0.y;   // v9 flipped
            const float b1 = (W & 1) ? c1.y : -c1.y;   // v8 flipped
            const float k00 = c0.x * c1.x;   // own
            const float k01 = c0.x * b1;     // v8 flipped
            const float k10 = a1 * c1.x;     // v9 flipped
            const float k11 = a1 * b1;       // both flipped
            const int p1 = ebase ^ (1 << 8);   // v8 flip
            const int p2 = ebase ^ (2 << 8);   // v9 flip
            const int p3 = ebase ^ (3 << 8);
#pragma unroll
            for (int r = 0; r < 4; ++r) {
                const float2 q1 = B[p1 + (r << 6)];
                const float2 q2 = B[p2 + (r << 6)];
                const float2 q3 = B[p3 + (r << 6)];
                re[r] = k00 * re[r] + k01 * q1.x + k10 * q2.x + k11 * q3.x;
                im[r] = k00 * im[r] + k01 * q1.y + k10 * q2.y + k11 * q3.y;
            }
        }
    };

    auto perm = [&]() {
        float2* B = buf[bs]; bs ^= 1;
#pragma unroll
        for (int r = 0; r < 4; ++r)
            B[ebase + (r << 6)] = make_float2(re[r], im[r]);
        __syncthreads();
#pragma unroll
        for (int r = 0; r < 4; ++r) {
            const float2 p = B[geidx[r]];
            re[r] = p.x;
            im[r] = p.y;
        }
    };

#pragma unroll 1
    for (int k = 0; k < 4; ++k) {
        if (k > 0) txdiag(k - 1);       // enc(prev)+rz0(k); k=0 rz0 = global phase (dropped)
        ry(2 * k);
        tdiag(3 + k);                   // rz2
        perm();
        tdiag(7 + k);                   // rz3
        ry(2 * k + 1);
        if (k < 3) tdiag(11 + k);       // rz5; k=3 is pure phase before |.|^2 (dropped)
        perm();
    }

    // out[b][w] = sum_s (re^2+im^2) * (1-2*bit_{9-w}(s))
    float pr[4];
#pragma unroll
    for (int r = 0; r < 4; ++r) pr[r] = re[r] * re[r] + im[r] * im[r];
    float S = 0.f;
#pragma unroll
    for (int r = 0; r < 4; ++r) S += pr[r];

    float acc[NW];
    acc[0] = (W & 2) ? -S : S;                 // bit9
    acc[1] = (W & 1) ? -S : S;                 // bit8
#pragma unroll
    for (int w = 2; w <= 7; ++w) {             // lane bit j = 7-w
        const int j = 7 - w;
        acc[w] = ((lane >> j) & 1) ? -S : S;
    }
    {   // wire 8: reg bit1 ; wire 9: reg bit0
        float t8 = 0.f, t9 = 0.f;
#pragma unroll
        for (int r = 0; r < 4; ++r) {
            t8 += (r & 2) ? -pr[r] : pr[r];
            t9 += (r & 1) ? -pr[r] : pr[r];
        }
        acc[8] = t8; acc[9] = t9;
    }
#pragma unroll
    for (int w = 0; w < NW; ++w) {
        float a = acc[w];
        a += fdpp<0xB1>(a);
        a += fdpp<0x4E>(a);
        a += fswz<0x101F>(a);
        a += fdpp<0x128>(a);
        a += fswz<0x401F>(a);
        a += __shfl_xor(a, 32, 64);
        acc[w] = a;
    }
    if (lane == 0) {
#pragma unroll
        for (int w = 0; w < NW; ++w) sred[W][w] = acc[w];
    }
    __syncthreads();
    if (t < NW) out[b * NW + t] = sred[0][t] + sred[1][t] + sred[2][t] + sred[3][t];
}

extern "C" void kernel_launch(void* const* d_in, const int* in_sizes, int n_in,
                              void* d_out, int out_size, void* d_ws, size_t ws_size,
                              hipStream_t stream) {
    const float* x      = (const float*)d_in[0];   // (2048, 10)
    const float* params = (const float*)d_in[1];   // (4, 6, 10)
    float* out          = (float*)d_out;           // (1, 2048, 10)
    float2* tab         = (float2*)d_ws;           // 14*1024 + 80 float2 = 115 KB
    (void)in_sizes; (void)n_in; (void)out_size; (void)ws_size;
    precompute_kernel<<<15, 1024, 0, stream>>>(params, tab);
    qsim_kernel<<<2048, 256, 0, stream>>>(x, tab, out);
}